// Round 1
// baseline (56.214 us; speedup 1.0000x reference)
//
#include <hip/hip_runtime.h>
#include <math.h>

// Sizes (fixed by the problem)
#define Bb 8
#define Tt 32
#define Hh 64
#define Ww 64
#define Cc 3
#define Ff 24
#define Uu 128

// ---------------------------------------------------------------------------
// Kernel 1: per-frame, per-channel statistics of x.
// stats[frame][c][25]:
//   [0]      total sum
//   [1..4]   row sums of rows {0,1,62,63}
//   [5..8]   col sums of cols {0,1,62,63}
//   [9..24]  x[r][w] for r in {0,1,62,63} x w in {0,1,62,63}  (idx 9+ri*4+wi)
// ---------------------------------------------------------------------------
__global__ void stats_kernel(const float* __restrict__ x, float* __restrict__ stats) {
    int n = blockIdx.x;                       // frame = b*T + t
    const float* xf = x + (size_t)n * (Hh * Ww * Cc);
    int tid  = threadIdx.x;                   // 0..255
    int row  = tid >> 2;
    int part = tid & 3;

    __shared__ float partial[256][3];
    __shared__ float rowsum[64][3];
    __shared__ float colv[64][12];            // [row][w4*3+c], w4 -> cols {0,1,62,63}

    // Each thread: 16 pixels (48 contiguous floats) of one row quarter.
    float s0 = 0.f, s1 = 0.f, s2 = 0.f;
    const float4* p4 = (const float4*)(xf + (row * Ww + part * 16) * Cc);
#pragma unroll
    for (int i = 0; i < 12; ++i) {
        float4 v = p4[i];
        int j = i * 4;
        float vv[4] = {v.x, v.y, v.z, v.w};
#pragma unroll
        for (int l = 0; l < 4; ++l) {
            int c = (j + l) % 3;
            if (c == 0) s0 += vv[l]; else if (c == 1) s1 += vv[l]; else s2 += vv[l];
        }
    }
    partial[tid][0] = s0; partial[tid][1] = s1; partial[tid][2] = s2;

    if (tid < 64) {
        int r = tid;
#pragma unroll
        for (int w4 = 0; w4 < 4; ++w4) {
            int w = (w4 < 2) ? w4 : 60 + w4;  // 0,1,62,63
#pragma unroll
            for (int c = 0; c < 3; ++c) colv[r][w4 * 3 + c] = xf[(r * Ww + w) * Cc + c];
        }
    }
    __syncthreads();

    if (part == 0) {
#pragma unroll
        for (int c = 0; c < 3; ++c)
            rowsum[row][c] = partial[tid][c] + partial[tid + 1][c]
                           + partial[tid + 2][c] + partial[tid + 3][c];
    }
    __syncthreads();

    float* out = stats + (size_t)n * 75;

    if (tid < 3) {                            // totals
        float t = 0.f;
        for (int r = 0; r < 64; ++r) t += rowsum[r][tid];
        out[tid * 25 + 0] = t;
    }
    if (tid >= 4 && tid < 16) {               // row sums rows {0,1,62,63}
        int k = tid - 4; int ri = k / 3, c = k % 3;
        int r = (ri < 2) ? ri : 60 + ri;
        out[c * 25 + 1 + ri] = rowsum[r][c];
    }
    if (tid >= 64 && tid < 76) {              // col sums cols {0,1,62,63}
        int k = tid - 64;
        float t = 0.f;
        for (int r = 0; r < 64; ++r) t += colv[r][k];
        int wi = k / 3, c = k % 3;
        out[c * 25 + 5 + wi] = t;
    }
    if (tid >= 128 && tid < 176) {            // 16 corner values x 3 channels
        int k = tid - 128; int pos = k / 3, c = k % 3;
        int ri = pos >> 2, wi = pos & 3;
        int r = (ri < 2) ? ri : 60 + ri;
        int w = (wi < 2) ? wi : 60 + wi;
        out[c * 25 + 9 + pos] = xf[(r * Ww + w) * Cc + c];
    }
}

// ---------------------------------------------------------------------------
// Kernel 2: feat[frame][24] = mean_{h,w} conv2(conv1(x)) via the stats.
// ---------------------------------------------------------------------------
__global__ void feat_kernel(const float* __restrict__ stats,
                            const float* __restrict__ w1, const float* __restrict__ b1,
                            const float* __restrict__ w2, const float* __restrict__ b2,
                            float* __restrict__ feat) {
    int n = blockIdx.x;
    int tid = threadIdx.x;                    // 64 threads
    __shared__ float st[75];                  // [c*25 + j]
    __shared__ float yst[24][9];              // Sy, rY0, rY63, cY0, cY63, y00,y0W,yH0,yHW

    if (tid < 75) st[tid] = stats[(size_t)n * 75 + tid];
    __syncthreads();

    if (tid < 24) {
        int f = tid;
        float Sy = 0, r0 = 0, r63 = 0, c0 = 0, c63 = 0, y00 = 0, y0W = 0, yH0 = 0, yHW = 0;
        for (int c = 0; c < 3; ++c) {
            const float* S = st + c * 25;
            float Sx = S[0];
            float rX[4] = {S[1], S[2], S[3], S[4]};   // rows 0,1,62,63
            float cX[4] = {S[5], S[6], S[7], S[8]};   // cols 0,1,62,63
            const float* X = S + 9;                   // X[ri*4+wi]
            #define W1(p, q) w1[(((p) * 3 + (q)) * 3 + c) * 24 + f]
            // Sy: full-region sums T_x(p,q)
#pragma unroll
            for (int p = 0; p < 3; ++p)
#pragma unroll
                for (int q = 0; q < 3; ++q) {
                    float t = Sx;
                    if (p == 0) t -= rX[3];
                    if (p == 2) t -= rX[0];
                    if (q == 0) t -= cX[3];
                    if (q == 2) t -= cX[0];
                    if (p == 0 && q == 0) t += X[3 * 4 + 3];
                    if (p == 0 && q == 2) t += X[3 * 4 + 0];
                    if (p == 2 && q == 0) t += X[0 * 4 + 3];
                    if (p == 2 && q == 2) t += X[0 * 4 + 0];
                    Sy += W1(p, q) * t;
                }
            // rowY(0) and rowY(63)
#pragma unroll
            for (int q = 0; q < 3; ++q) {
                float Rr0  = rX[0] - ((q == 0) ? X[0 * 4 + 3] : 0.f) - ((q == 2) ? X[0 * 4 + 0] : 0.f);
                float Rr1  = rX[1] - ((q == 0) ? X[1 * 4 + 3] : 0.f) - ((q == 2) ? X[1 * 4 + 0] : 0.f);
                float Rr62 = rX[2] - ((q == 0) ? X[2 * 4 + 3] : 0.f) - ((q == 2) ? X[2 * 4 + 0] : 0.f);
                float Rr63 = rX[3] - ((q == 0) ? X[3 * 4 + 3] : 0.f) - ((q == 2) ? X[3 * 4 + 0] : 0.f);
                r0  += W1(1, q) * Rr0  + W1(2, q) * Rr1;
                r63 += W1(0, q) * Rr62 + W1(1, q) * Rr63;
            }
            // colY(0) and colY(63)
#pragma unroll
            for (int p = 0; p < 3; ++p) {
                float Rc0  = cX[0] - ((p == 0) ? X[3 * 4 + 0] : 0.f) - ((p == 2) ? X[0 * 4 + 0] : 0.f);
                float Rc1  = cX[1] - ((p == 0) ? X[3 * 4 + 1] : 0.f) - ((p == 2) ? X[0 * 4 + 1] : 0.f);
                float Rc62 = cX[2] - ((p == 0) ? X[3 * 4 + 2] : 0.f) - ((p == 2) ? X[0 * 4 + 2] : 0.f);
                float Rc63 = cX[3] - ((p == 0) ? X[3 * 4 + 3] : 0.f) - ((p == 2) ? X[0 * 4 + 3] : 0.f);
                c0  += W1(p, 1) * Rc0  + W1(p, 2) * Rc1;
                c63 += W1(p, 0) * Rc62 + W1(p, 1) * Rc63;
            }
            // corners of y
            y00 += W1(1, 1) * X[0 * 4 + 0] + W1(1, 2) * X[0 * 4 + 1]
                 + W1(2, 1) * X[1 * 4 + 0] + W1(2, 2) * X[1 * 4 + 1];
            y0W += W1(1, 0) * X[0 * 4 + 2] + W1(1, 1) * X[0 * 4 + 3]
                 + W1(2, 0) * X[1 * 4 + 2] + W1(2, 1) * X[1 * 4 + 3];
            yH0 += W1(0, 1) * X[2 * 4 + 0] + W1(0, 2) * X[2 * 4 + 1]
                 + W1(1, 1) * X[3 * 4 + 0] + W1(1, 2) * X[3 * 4 + 1];
            yHW += W1(0, 0) * X[2 * 4 + 2] + W1(0, 1) * X[2 * 4 + 3]
                 + W1(1, 0) * X[3 * 4 + 2] + W1(1, 1) * X[3 * 4 + 3];
            #undef W1
        }
        float bb = b1[f];
        yst[f][0] = Sy + 4096.f * bb;
        yst[f][1] = r0 + 64.f * bb;
        yst[f][2] = r63 + 64.f * bb;
        yst[f][3] = c0 + 64.f * bb;
        yst[f][4] = c63 + 64.f * bb;
        yst[f][5] = y00 + bb; yst[f][6] = y0W + bb;
        yst[f][7] = yH0 + bb; yst[f][8] = yHW + bb;
    }
    __syncthreads();

    if (tid < 24) {
        int g = tid;
        float acc = 0.f;
        for (int f = 0; f < 24; ++f) {
            float Sy = yst[f][0], rY0 = yst[f][1], rY63 = yst[f][2], cY0 = yst[f][3], cY63 = yst[f][4];
            float yc00 = yst[f][5], yc0W = yst[f][6], ycH0 = yst[f][7], ycHW = yst[f][8];
#pragma unroll
            for (int p = 0; p < 3; ++p)
#pragma unroll
                for (int q = 0; q < 3; ++q) {
                    float t = Sy;
                    if (p == 0) t -= rY63;
                    if (p == 2) t -= rY0;
                    if (q == 0) t -= cY63;
                    if (q == 2) t -= cY0;
                    if (p == 0 && q == 0) t += ycHW;
                    if (p == 0 && q == 2) t += ycH0;
                    if (p == 2 && q == 0) t += yc0W;
                    if (p == 2 && q == 2) t += yc00;
                    acc += w2[(((p * 3 + q) * 24 + f) * 24) + g] * t;
                }
        }
        feat[(size_t)n * 24 + g] = b2[g] + acc * (1.f / 4096.f);
    }
}

// ---------------------------------------------------------------------------
// Kernel 3: input-part of gate preactivations.
// G[t][b][g][u] = bias_g[u] + feat[b*T+t, :24] @ W_g[0:24, u]
// ---------------------------------------------------------------------------
__global__ void gpre_kernel(const float* __restrict__ feat,
                            const float* __restrict__ Wf, const float* __restrict__ bf,
                            const float* __restrict__ Wi, const float* __restrict__ bi,
                            const float* __restrict__ Wc, const float* __restrict__ bc,
                            const float* __restrict__ Wo, const float* __restrict__ bo,
                            float* __restrict__ G) {
    int blk = blockIdx.x;                     // t*8 + b
    int t = blk >> 3, b = blk & 7;
    int tid = threadIdx.x;                    // g*128 + u
    int g = tid >> 7, u = tid & 127;
    const float* W    = (g == 0) ? Wf : (g == 1) ? Wi : (g == 2) ? Wc : Wo;
    const float* bias = (g == 0) ? bf : (g == 1) ? bi : (g == 2) ? bc : bo;
    int n = b * Tt + t;
    float acc = bias[u];
#pragma unroll
    for (int k = 0; k < Ff; ++k) acc += feat[(size_t)n * Ff + k] * W[k * Uu + u];
    G[(size_t)blk * 512 + tid] = acc;
}

// ---------------------------------------------------------------------------
// Kernel 4: LSTM recurrence + output projection. One block per batch element.
// ---------------------------------------------------------------------------
__global__ __launch_bounds__(512, 2) void lstm_kernel(
        const float* __restrict__ G,
        const float* __restrict__ Wf, const float* __restrict__ Wi,
        const float* __restrict__ Wc, const float* __restrict__ Wo,
        const float* __restrict__ out_w, const float* __restrict__ out_b,
        float* __restrict__ out) {
    int b = blockIdx.x;
    int tid = threadIdx.x;                    // g*128 + u
    int g = tid >> 7, u = tid & 127;
    const float* W = (g == 0) ? Wf : (g == 1) ? Wi : (g == 2) ? Wc : Wo;

    // Preload recurrent weights (rows 24..151, this thread's column u).
    float wreg[Uu];
#pragma unroll
    for (int k = 0; k < Uu; ++k) wreg[k] = W[(Ff + k) * Uu + u];

    __shared__ float hs[Uu];
    __shared__ float cs[Uu];
    __shared__ float act[512];
    __shared__ float red[2];

    if (tid < Uu) { hs[tid] = 0.f; cs[tid] = 0.f; }
    float ow = (tid < Uu) ? out_w[tid] : 0.f;
    float outb = out_b[0];
    __syncthreads();

    for (int t = 0; t < Tt; ++t) {
        float gx = G[((size_t)(t * Bb + b)) * 512 + tid];
        float acc = 0.f;
        const float4* h4 = (const float4*)hs;
#pragma unroll
        for (int k4 = 0; k4 < Uu / 4; ++k4) {
            float4 hv = h4[k4];
            acc += wreg[k4 * 4 + 0] * hv.x;
            acc += wreg[k4 * 4 + 1] * hv.y;
            acc += wreg[k4 * 4 + 2] * hv.z;
            acc += wreg[k4 * 4 + 3] * hv.w;
        }
        acc += gx;
        float a = (g == 2) ? tanhf(acc) : 1.f / (1.f + expf(-acc));
        act[tid] = a;
        __syncthreads();
        if (tid < Uu) {
            float c_new = cs[tid] * act[tid] + act[Uu + tid] * act[2 * Uu + tid];
            float h_new = tanhf(c_new) * act[3 * Uu + tid];
            cs[tid] = c_new;
            hs[tid] = h_new;
            float p = h_new * ow;
#pragma unroll
            for (int off = 32; off > 0; off >>= 1) p += __shfl_down(p, off);
            if ((tid & 63) == 0) red[tid >> 6] = p;
        }
        __syncthreads();
        if (tid == 0) out[b * Tt + t] = red[0] + red[1] + outb;
    }
}

// ---------------------------------------------------------------------------
extern "C" void kernel_launch(void* const* d_in, const int* in_sizes, int n_in,
                              void* d_out, int out_size, void* d_ws, size_t ws_size,
                              hipStream_t stream) {
    const float* x   = (const float*)d_in[0];
    const float* w1  = (const float*)d_in[1];
    const float* b1  = (const float*)d_in[2];
    const float* w2  = (const float*)d_in[3];
    const float* b2  = (const float*)d_in[4];
    const float* Wf  = (const float*)d_in[5];
    const float* bf  = (const float*)d_in[6];
    const float* Wi  = (const float*)d_in[7];
    const float* bi  = (const float*)d_in[8];
    const float* Wc  = (const float*)d_in[9];
    const float* bc  = (const float*)d_in[10];
    const float* Wo  = (const float*)d_in[11];
    const float* bo  = (const float*)d_in[12];
    const float* ow  = (const float*)d_in[13];
    const float* ob  = (const float*)d_in[14];
    float* out = (float*)d_out;

    float* ws    = (float*)d_ws;
    float* stats = ws;                        // 256*75   = 19200 floats
    float* feat  = ws + 19200;                // 256*24   = 6144 floats
    float* G     = ws + 25344;                // 256*512  = 131072 floats

    stats_kernel<<<Bb * Tt, 256, 0, stream>>>(x, stats);
    feat_kernel<<<Bb * Tt, 64, 0, stream>>>(stats, w1, b1, w2, b2, feat);
    gpre_kernel<<<Bb * Tt, 512, 0, stream>>>(feat, Wf, bf, Wi, bi, Wc, bc, Wo, bo, G);
    lstm_kernel<<<Bb, 512, 0, stream>>>(G, Wf, Wi, Wc, Wo, ow, ob, out);
}

// Round 2
// 42.964 us; speedup vs baseline: 1.3084x; 1.3084x over previous
//
#include <hip/hip_runtime.h>
#include <math.h>

// Sizes (fixed by the problem)
#define Bb 8
#define Tt 32
#define Hh 64
#define Ww 64
#define Cc 3
#define Ff 24
#define Uu 128

// ---------------------------------------------------------------------------
// Kernel 1: fused per-frame stats + analytic double-conv + global-avg-pool.
// feat[frame][24] = mean_{h,w} conv2(conv1(x)) computed from 25 region stats
// per channel (linear convs + SAME padding collapse under the mean).
// ---------------------------------------------------------------------------
__global__ void convfeat_kernel(const float* __restrict__ x,
                                const float* __restrict__ w1, const float* __restrict__ b1,
                                const float* __restrict__ w2, const float* __restrict__ b2,
                                float* __restrict__ feat) {
    int n = blockIdx.x;                       // frame = b*T + t
    const float* xf = x + (size_t)n * (Hh * Ww * Cc);
    int tid  = threadIdx.x;                   // 0..255
    int row  = tid >> 2;
    int part = tid & 3;

    __shared__ float partial[256][3];
    __shared__ float rowsum[64][3];
    __shared__ float colv[64][12];            // [row][w4*3+c], w4 -> cols {0,1,62,63}
    __shared__ float st[75];                  // [c*25 + j]
    __shared__ float yst[24][9];              // Sy, rY0, rY63, cY0, cY63, y00,y0W,yH0,yHW

    // ---- stats phase: each thread sums 16 pixels (48 contiguous floats) ----
    float s0 = 0.f, s1 = 0.f, s2 = 0.f;
    const float4* p4 = (const float4*)(xf + (row * Ww + part * 16) * Cc);
#pragma unroll
    for (int i = 0; i < 12; ++i) {
        float4 v = p4[i];
        int j = i * 4;
        float vv[4] = {v.x, v.y, v.z, v.w};
#pragma unroll
        for (int l = 0; l < 4; ++l) {
            int c = (j + l) % 3;
            if (c == 0) s0 += vv[l]; else if (c == 1) s1 += vv[l]; else s2 += vv[l];
        }
    }
    partial[tid][0] = s0; partial[tid][1] = s1; partial[tid][2] = s2;

    if (tid < 64) {
        int r = tid;
#pragma unroll
        for (int w4 = 0; w4 < 4; ++w4) {
            int w = (w4 < 2) ? w4 : 60 + w4;  // 0,1,62,63
#pragma unroll
            for (int c = 0; c < 3; ++c) colv[r][w4 * 3 + c] = xf[(r * Ww + w) * Cc + c];
        }
    }
    __syncthreads();

    if (part == 0) {
#pragma unroll
        for (int c = 0; c < 3; ++c)
            rowsum[row][c] = partial[tid][c] + partial[tid + 1][c]
                           + partial[tid + 2][c] + partial[tid + 3][c];
    }
    __syncthreads();

    if (tid < 3) {                            // totals
        float t = 0.f;
        for (int r = 0; r < 64; ++r) t += rowsum[r][tid];
        st[tid * 25 + 0] = t;
    }
    if (tid >= 4 && tid < 16) {               // row sums rows {0,1,62,63}
        int k = tid - 4; int ri = k / 3, c = k % 3;
        int r = (ri < 2) ? ri : 60 + ri;
        st[c * 25 + 1 + ri] = rowsum[r][c];
    }
    if (tid >= 64 && tid < 76) {              // col sums cols {0,1,62,63}
        int k = tid - 64;
        float t = 0.f;
        for (int r = 0; r < 64; ++r) t += colv[r][k];
        int wi = k / 3, c = k % 3;
        st[c * 25 + 5 + wi] = t;
    }
    if (tid >= 128 && tid < 176) {            // 16 corner values x 3 channels
        int k = tid - 128; int pos = k / 3, c = k % 3;
        int ri = pos >> 2, wi = pos & 3;
        int r = (ri < 2) ? ri : 60 + ri;
        int w = (wi < 2) ? wi : 60 + wi;
        st[c * 25 + 9 + pos] = xf[(r * Ww + w) * Cc + c];
    }
    __syncthreads();

    // ---- conv1 stats ----
    if (tid < 24) {
        int f = tid;
        float Sy = 0, r0 = 0, r63 = 0, c0 = 0, c63 = 0, y00 = 0, y0W = 0, yH0 = 0, yHW = 0;
        for (int c = 0; c < 3; ++c) {
            const float* S = st + c * 25;
            float Sx = S[0];
            float rX[4] = {S[1], S[2], S[3], S[4]};   // rows 0,1,62,63
            float cX[4] = {S[5], S[6], S[7], S[8]};   // cols 0,1,62,63
            const float* X = S + 9;                   // X[ri*4+wi]
            #define W1(p, q) w1[(((p) * 3 + (q)) * 3 + c) * 24 + f]
#pragma unroll
            for (int p = 0; p < 3; ++p)
#pragma unroll
                for (int q = 0; q < 3; ++q) {
                    float t = Sx;
                    if (p == 0) t -= rX[3];
                    if (p == 2) t -= rX[0];
                    if (q == 0) t -= cX[3];
                    if (q == 2) t -= cX[0];
                    if (p == 0 && q == 0) t += X[3 * 4 + 3];
                    if (p == 0 && q == 2) t += X[3 * 4 + 0];
                    if (p == 2 && q == 0) t += X[0 * 4 + 3];
                    if (p == 2 && q == 2) t += X[0 * 4 + 0];
                    Sy += W1(p, q) * t;
                }
#pragma unroll
            for (int q = 0; q < 3; ++q) {
                float Rr0  = rX[0] - ((q == 0) ? X[0 * 4 + 3] : 0.f) - ((q == 2) ? X[0 * 4 + 0] : 0.f);
                float Rr1  = rX[1] - ((q == 0) ? X[1 * 4 + 3] : 0.f) - ((q == 2) ? X[1 * 4 + 0] : 0.f);
                float Rr62 = rX[2] - ((q == 0) ? X[2 * 4 + 3] : 0.f) - ((q == 2) ? X[2 * 4 + 0] : 0.f);
                float Rr63 = rX[3] - ((q == 0) ? X[3 * 4 + 3] : 0.f) - ((q == 2) ? X[3 * 4 + 0] : 0.f);
                r0  += W1(1, q) * Rr0  + W1(2, q) * Rr1;
                r63 += W1(0, q) * Rr62 + W1(1, q) * Rr63;
            }
#pragma unroll
            for (int p = 0; p < 3; ++p) {
                float Rc0  = cX[0] - ((p == 0) ? X[3 * 4 + 0] : 0.f) - ((p == 2) ? X[0 * 4 + 0] : 0.f);
                float Rc1  = cX[1] - ((p == 0) ? X[3 * 4 + 1] : 0.f) - ((p == 2) ? X[0 * 4 + 1] : 0.f);
                float Rc62 = cX[2] - ((p == 0) ? X[3 * 4 + 2] : 0.f) - ((p == 2) ? X[0 * 4 + 2] : 0.f);
                float Rc63 = cX[3] - ((p == 0) ? X[3 * 4 + 3] : 0.f) - ((p == 2) ? X[0 * 4 + 3] : 0.f);
                c0  += W1(p, 1) * Rc0  + W1(p, 2) * Rc1;
                c63 += W1(p, 0) * Rc62 + W1(p, 1) * Rc63;
            }
            y00 += W1(1, 1) * X[0 * 4 + 0] + W1(1, 2) * X[0 * 4 + 1]
                 + W1(2, 1) * X[1 * 4 + 0] + W1(2, 2) * X[1 * 4 + 1];
            y0W += W1(1, 0) * X[0 * 4 + 2] + W1(1, 1) * X[0 * 4 + 3]
                 + W1(2, 0) * X[1 * 4 + 2] + W1(2, 1) * X[1 * 4 + 3];
            yH0 += W1(0, 1) * X[2 * 4 + 0] + W1(0, 2) * X[2 * 4 + 1]
                 + W1(1, 1) * X[3 * 4 + 0] + W1(1, 2) * X[3 * 4 + 1];
            yHW += W1(0, 0) * X[2 * 4 + 2] + W1(0, 1) * X[2 * 4 + 3]
                 + W1(1, 0) * X[3 * 4 + 2] + W1(1, 1) * X[3 * 4 + 3];
            #undef W1
        }
        float bb = b1[f];
        yst[f][0] = Sy + 4096.f * bb;
        yst[f][1] = r0 + 64.f * bb;
        yst[f][2] = r63 + 64.f * bb;
        yst[f][3] = c0 + 64.f * bb;
        yst[f][4] = c63 + 64.f * bb;
        yst[f][5] = y00 + bb; yst[f][6] = y0W + bb;
        yst[f][7] = yH0 + bb; yst[f][8] = yHW + bb;
    }
    __syncthreads();

    // ---- conv2 + mean ----
    if (tid < 24) {
        int g = tid;
        float acc = 0.f;
        for (int f = 0; f < 24; ++f) {
            float Sy = yst[f][0], rY0 = yst[f][1], rY63 = yst[f][2], cY0 = yst[f][3], cY63 = yst[f][4];
            float yc00 = yst[f][5], yc0W = yst[f][6], ycH0 = yst[f][7], ycHW = yst[f][8];
#pragma unroll
            for (int p = 0; p < 3; ++p)
#pragma unroll
                for (int q = 0; q < 3; ++q) {
                    float t = Sy;
                    if (p == 0) t -= rY63;
                    if (p == 2) t -= rY0;
                    if (q == 0) t -= cY63;
                    if (q == 2) t -= cY0;
                    if (p == 0 && q == 0) t += ycHW;
                    if (p == 0 && q == 2) t += ycH0;
                    if (p == 2 && q == 0) t += yc0W;
                    if (p == 2 && q == 2) t += yc00;
                    acc += w2[(((p * 3 + q) * 24 + f) * 24) + g] * t;
                }
        }
        feat[(size_t)n * 24 + g] = b2[g] + acc * (1.f / 4096.f);
    }
}

// ---------------------------------------------------------------------------
// Kernel 2: input-part of gate preactivations (embarrassingly parallel).
// G[t*8+b][g*128+u] = bias_g[u] + feat[b*T+t, :24] @ W_g[0:24, u]
// ---------------------------------------------------------------------------
__global__ void gpre_kernel(const float* __restrict__ feat,
                            const float* __restrict__ Wf, const float* __restrict__ bf,
                            const float* __restrict__ Wi, const float* __restrict__ bi,
                            const float* __restrict__ Wc, const float* __restrict__ bc,
                            const float* __restrict__ Wo, const float* __restrict__ bo,
                            float* __restrict__ G) {
    int blk = blockIdx.x;                     // t*8 + b
    int t = blk >> 3, b = blk & 7;
    int tid = threadIdx.x;                    // g*128 + u
    int g = tid >> 7, u = tid & 127;
    const float* W    = (g == 0) ? Wf : (g == 1) ? Wi : (g == 2) ? Wc : Wo;
    const float* bias = (g == 0) ? bf : (g == 1) ? bi : (g == 2) ? bc : bo;
    int n = b * Tt + t;
    float acc = bias[u];
#pragma unroll
    for (int k = 0; k < Ff; ++k) acc += feat[(size_t)n * Ff + k] * W[k * Uu + u];
    G[(size_t)blk * 512 + tid] = acc;
}

// ---------------------------------------------------------------------------
// Kernel 3: LSTM recurrence. One block per batch element, 512 threads.
// Thread (u = tid&127, q = tid>>7):
//   phase 1: partial dots for ALL 4 gates over k-chunk [32q, 32q+32)
//            (h reads are wave-uniform broadcasts; each h reused by 4 FMAs)
//   phase 3: acts as (gate=q, unit=u): sum 4 partials + gx -> activation
//   phase 4: tid<128 update c,h; h history kept in LDS for the epilogue.
// ---------------------------------------------------------------------------
__global__ __launch_bounds__(512, 1) void lstm_kernel(
        const float* __restrict__ G,
        const float* __restrict__ Wf, const float* __restrict__ Wi,
        const float* __restrict__ Wc, const float* __restrict__ Wo,
        const float* __restrict__ out_w, const float* __restrict__ out_b,
        float* __restrict__ out) {
    int b = blockIdx.x;
    int tid = threadIdx.x;
    int u = tid & 127;
    int q = tid >> 7;                         // k-chunk (phase 1) / gate (phase 3)

    // Recurrent weights for this thread's k-chunk, all 4 gates: 128 VGPRs.
    float wreg[32][4];
    {
        const float* W0 = Wf + (size_t)(Ff + q * 32) * Uu + u;
        const float* W1 = Wi + (size_t)(Ff + q * 32) * Uu + u;
        const float* W2 = Wc + (size_t)(Ff + q * 32) * Uu + u;
        const float* W3 = Wo + (size_t)(Ff + q * 32) * Uu + u;
#pragma unroll
        for (int j = 0; j < 32; ++j) {
            wreg[j][0] = W0[j * Uu];
            wreg[j][1] = W1[j * Uu];
            wreg[j][2] = W2[j * Uu];
            wreg[j][3] = W3[j * Uu];
        }
    }

    __shared__ float hs[Uu];
    __shared__ float part[4][4][Uu];          // [k-chunk][gate][u]
    __shared__ float act[4][Uu];              // [gate][u]
    __shared__ float hist[Tt][Uu];

    float cs = 0.f;                           // cell state lives in tid<128 regs
    if (tid < Uu) hs[tid] = 0.f;
    __syncthreads();

    for (int t = 0; t < Tt; ++t) {
        // gx for phase 3 — issue early, latency hidden under phase 1.
        float gx = G[((size_t)(t * Bb + b)) * 512 + tid];

        // phase 1: 128 FMAs, 4 independent accumulator chains.
        float p0 = 0.f, p1 = 0.f, p2 = 0.f, p3 = 0.f;
        const float4* h4 = (const float4*)(hs + q * 32);
#pragma unroll
        for (int j4 = 0; j4 < 8; ++j4) {
            float4 hv = h4[j4];
            p0 += wreg[j4 * 4 + 0][0] * hv.x; p1 += wreg[j4 * 4 + 0][1] * hv.x;
            p2 += wreg[j4 * 4 + 0][2] * hv.x; p3 += wreg[j4 * 4 + 0][3] * hv.x;
            p0 += wreg[j4 * 4 + 1][0] * hv.y; p1 += wreg[j4 * 4 + 1][1] * hv.y;
            p2 += wreg[j4 * 4 + 1][2] * hv.y; p3 += wreg[j4 * 4 + 1][3] * hv.y;
            p0 += wreg[j4 * 4 + 2][0] * hv.z; p1 += wreg[j4 * 4 + 2][1] * hv.z;
            p2 += wreg[j4 * 4 + 2][2] * hv.z; p3 += wreg[j4 * 4 + 2][3] * hv.z;
            p0 += wreg[j4 * 4 + 3][0] * hv.w; p1 += wreg[j4 * 4 + 3][1] * hv.w;
            p2 += wreg[j4 * 4 + 3][2] * hv.w; p3 += wreg[j4 * 4 + 3][3] * hv.w;
        }
        part[q][0][u] = p0; part[q][1][u] = p1;
        part[q][2][u] = p2; part[q][3][u] = p3;
        __syncthreads();

        // phase 3: this thread = (gate q, unit u). One transcendental each.
        float s = part[0][q][u] + part[1][q][u] + part[2][q][u] + part[3][q][u] + gx;
        float a = (q == 2) ? tanhf(s) : 1.f / (1.f + expf(-s));
        act[q][u] = a;
        __syncthreads();

        // phase 4: state update on 128 threads.
        if (tid < Uu) {
            float f = act[0][u], i = act[1][u], g = act[2][u], o = act[3][u];
            cs = cs * f + i * g;
            float hn = tanhf(cs) * o;
            hs[u] = hn;
            hist[t][u] = hn;
        }
        __syncthreads();
    }

    // Epilogue: out[b][t] = hist[t] . out_w + out_b, 16 threads per t.
    int tt = tid >> 4, j = tid & 15;
    const float4* hh = (const float4*)(&hist[tt][j * 8]);
    float4 a0 = hh[0], a1 = hh[1];
    const float* owp = out_w + j * 8;
    float pw = a0.x * owp[0] + a0.y * owp[1] + a0.z * owp[2] + a0.w * owp[3]
             + a1.x * owp[4] + a1.y * owp[5] + a1.z * owp[6] + a1.w * owp[7];
#pragma unroll
    for (int off = 8; off > 0; off >>= 1) pw += __shfl_down(pw, off, 16);
    if (j == 0) out[b * Tt + tt] = pw + out_b[0];
}

// ---------------------------------------------------------------------------
extern "C" void kernel_launch(void* const* d_in, const int* in_sizes, int n_in,
                              void* d_out, int out_size, void* d_ws, size_t ws_size,
                              hipStream_t stream) {
    const float* x   = (const float*)d_in[0];
    const float* w1  = (const float*)d_in[1];
    const float* b1  = (const float*)d_in[2];
    const float* w2  = (const float*)d_in[3];
    const float* b2  = (const float*)d_in[4];
    const float* Wf  = (const float*)d_in[5];
    const float* bf  = (const float*)d_in[6];
    const float* Wi  = (const float*)d_in[7];
    const float* bi  = (const float*)d_in[8];
    const float* Wc  = (const float*)d_in[9];
    const float* bc  = (const float*)d_in[10];
    const float* Wo  = (const float*)d_in[11];
    const float* bo  = (const float*)d_in[12];
    const float* ow  = (const float*)d_in[13];
    const float* ob  = (const float*)d_in[14];
    float* out = (float*)d_out;

    float* ws   = (float*)d_ws;
    float* feat = ws;                         // 256*24  = 6144 floats
    float* G    = ws + 6144;                  // 256*512 = 131072 floats

    convfeat_kernel<<<Bb * Tt, 256, 0, stream>>>(x, w1, b1, w2, b2, feat);
    gpre_kernel<<<Bb * Tt, 512, 0, stream>>>(feat, Wf, bf, Wi, bi, Wc, bc, Wo, bo, G);
    lstm_kernel<<<Bb, 512, 0, stream>>>(G, Wf, Wi, Wc, Wo, ow, ob, out);
}